// Round 1
// baseline (439.787 us; speedup 1.0000x reference)
//
#include <hip/hip_runtime.h>
#include <hip/hip_bf16.h>

typedef __hip_bfloat16 bf16;
typedef unsigned short u16;
typedef float f32x4 __attribute__((ext_vector_type(4)));
typedef __bf16 bf16x8 __attribute__((ext_vector_type(8)));
typedef u16 u16x8 __attribute__((ext_vector_type(8)));

#define DMODEL 1024
#define NH 16
#define HD 64
#define QKV_LD 3072

typedef __attribute__((address_space(1))) const void* as1_cvp;
typedef __attribute__((address_space(3))) void* as3_vp;

__device__ __forceinline__ void gload_lds16(const void* g, void* l) {
  __builtin_amdgcn_global_load_lds((as1_cvp)g, (as3_vp)l, 16, 0, 0);
}

__device__ __forceinline__ f32x4 mfma16(bf16x8 a, bf16x8 b, f32x4 c) {
  return __builtin_amdgcn_mfma_f32_16x16x32_bf16(a, b, c, 0, 0, 0);
}

// ---------------- fp32 -> bf16 conversion, 4 elems/thread ----------------
__global__ __launch_bounds__(256) void cvt_kernel(const float* __restrict__ src,
                                                  bf16* __restrict__ dst, int n) {
  int i = (blockIdx.x * 256 + threadIdx.x) * 4;
  if (i >= n) return;
  float4 v = *(const float4*)(src + i);
  union { ushort4 u; bf16 h[4]; } o;
  o.h[0] = __float2bfloat16(v.x);
  o.h[1] = __float2bfloat16(v.y);
  o.h[2] = __float2bfloat16(v.z);
  o.h[3] = __float2bfloat16(v.w);
  *(ushort4*)(dst + i) = o.u;
}

// ---------------- RoPE on Q and K regions of QKV, in place ----------------
// Also folds the 1/sqrt(HD)=0.125 score scale into Q (exact in bf16).
__global__ __launch_bounds__(256) void rope_kernel(bf16* __restrict__ qkv) {
  int idx = blockIdx.x * 256 + threadIdx.x;   // 4096 rows * 2 regions * 512 pairs
  int p = idx & 511;          // pair within row-region
  int s = (idx >> 9) & 4095;  // sequence position
  int region = idx >> 21;     // 0 = Q, 1 = K
  int i = p & 31;             // pair index within head
  int h = p >> 5;             // head
  long base = (long)s * QKV_LD + region * DMODEL + h * HD + 2 * i;
  float x1 = __bfloat162float(qkv[base]);
  float x2 = __bfloat162float(qkv[base + 1]);
  float invf = powf(10000.0f, -(float)(2 * i) / 64.0f);
  float ang = (float)s * invf;
  float sn, cs;
  sincosf(ang, &sn, &cs);
  float scale = (region == 0) ? 0.125f : 1.0f;
  float r1 = (x1 * cs - x2 * sn) * scale;
  float r2 = (x1 * sn + x2 * cs) * scale;
  qkv[base]     = __float2bfloat16(r1);
  qkv[base + 1] = __float2bfloat16(r2);
}

// ---------------- NT GEMM: C[M,N] = A[M,K] * B[N,K]^T ----------------
// 128x128 tile, BK=32, 4 waves (2x2), 16x16x32 bf16 MFMA, global_load_lds staging.
template <int OUT_BF16>
__global__ __launch_bounds__(256) void gemm_bt(const bf16* __restrict__ A,
                                               const bf16* __restrict__ B,
                                               void* __restrict__ Cout,
                                               const float* __restrict__ bias,
                                               int M, int N, int K) {
  __shared__ __align__(16) bf16 As[128 * 32];
  __shared__ __align__(16) bf16 Bs[128 * 32];
  const int tid = threadIdx.x;
  const int lane = tid & 63;
  const int wid = tid >> 6;
  const int brow = blockIdx.y * 128;
  const int bcol = blockIdx.x * 128;
  const int wr = wid >> 1, wc = wid & 1;

  f32x4 acc[4][4] = {};

  const int srow = lane >> 2;        // 0..15
  const int scol = (lane & 3) * 8;   // 0,8,16,24
  const bf16* Ag = A + (long)(brow + wid * 32 + srow) * K + scol;
  const bf16* Bg = B + (long)(bcol + wid * 32 + srow) * K + scol;
  bf16* AsW = As + wid * 32 * 32;    // wave-uniform LDS base (linear dest)
  bf16* BsW = Bs + wid * 32 * 32;
  const int kof = (lane >> 4) * 8;
  const int r16 = lane & 15;

  for (int k0 = 0; k0 < K; k0 += 32) {
    __syncthreads();
    gload_lds16(Ag + k0, AsW);
    gload_lds16(Ag + k0 + (long)16 * K, AsW + 16 * 32);
    gload_lds16(Bg + k0, BsW);
    gload_lds16(Bg + k0 + (long)16 * K, BsW + 16 * 32);
    __syncthreads();
    bf16x8 af[4], bfr[4];
#pragma unroll
    for (int m = 0; m < 4; ++m)
      af[m] = *(const bf16x8*)(As + (wr * 64 + m * 16 + r16) * 32 + kof);
#pragma unroll
    for (int n = 0; n < 4; ++n)
      bfr[n] = *(const bf16x8*)(Bs + (wc * 64 + n * 16 + r16) * 32 + kof);
#pragma unroll
    for (int m = 0; m < 4; ++m)
#pragma unroll
      for (int n = 0; n < 4; ++n)
        acc[m][n] = mfma16(af[m], bfr[n], acc[m][n]);
  }

  const int r0 = (lane >> 4) * 4;
#pragma unroll
  for (int m = 0; m < 4; ++m) {
#pragma unroll
    for (int n = 0; n < 4; ++n) {
      int row = brow + wr * 64 + m * 16 + r0;
      int col = bcol + wc * 64 + n * 16 + r16;
#pragma unroll
      for (int r = 0; r < 4; ++r) {
        if (OUT_BF16) {
          ((bf16*)Cout)[(long)(row + r) * N + col] = __float2bfloat16(acc[m][n][r]);
        } else {
          ((float*)Cout)[(long)(row + r) * N + col] = acc[m][n][r] + bias[col];
        }
      }
    }
  }
}

// ---------------- causal flash attention ----------------
// grid (64 qblocks, 16 heads), 256 threads = 4 waves; each wave owns 16 q rows.
// KV blocks of 32. K in LDS [32][72] (144B stride: aligned + ~2-way banks).
// V transposed in LDS [64][40]. P staged per-wave through padded LDS.
__global__ __launch_bounds__(256) void attn_kernel(const bf16* __restrict__ qkv,
                                                   bf16* __restrict__ ctx) {
  __shared__ __align__(16) bf16 Ks[32][72];
  __shared__ __align__(16) bf16 Vt[64][40];
  __shared__ __align__(16) bf16 Ps[4][16][40];

  const int tid = threadIdx.x;
  const int lane = tid & 63;
  const int wid = tid >> 6;
  const int h = blockIdx.y;
  const int qblk = blockIdx.x;
  const int q0 = qblk * 64 + wid * 16;
  const int r16 = lane & 15;
  const int kof = (lane >> 4) * 8;
  const long qcol = h * HD;
  const long kcol = DMODEL + h * HD;
  const long vcol = 2 * DMODEL + h * HD;

  // Q fragments (scale already folded in by rope_kernel)
  bf16x8 qf0 = *(const bf16x8*)(qkv + (long)(q0 + r16) * QKV_LD + qcol + kof);
  bf16x8 qf1 = *(const bf16x8*)(qkv + (long)(q0 + r16) * QKV_LD + qcol + 32 + kof);

  float m_r[4], l_r[4];
  f32x4 acc[4] = {};
#pragma unroll
  for (int r = 0; r < 4; ++r) { m_r[r] = -1e30f; l_r[r] = 0.0f; }

  const int kr = tid >> 3;        // K-stage row 0..31
  const int kc = (tid & 7) * 8;   // K-stage col
  const int vk0 = wid * 8;        // V-stage k base (d = lane)

  const int nkb = qblk * 2 + 2;
  for (int kb = 0; kb < nkb; ++kb) {
    const int kvbase = kb * 32;
    __syncthreads();
    // stage K block [32][64] -> Ks
    *(u16x8*)(&Ks[kr][kc]) =
        *(const u16x8*)((const u16*)qkv + (long)(kvbase + kr) * QKV_LD + kcol + kc);
    // stage V block transposed: thread owns (d=lane, k=vk0..vk0+7)
    {
      u16x8 vv;
#pragma unroll
      for (int j = 0; j < 8; ++j)
        vv[j] = ((const u16*)qkv)[(long)(kvbase + vk0 + j) * QKV_LD + vcol + lane];
      *(u16x8*)(&Vt[lane][vk0]) = vv;
    }
    __syncthreads();

    // S = Q K^T  (K dim = head dim, 2 halves of 32)
    f32x4 c0 = {0.f, 0.f, 0.f, 0.f}, c1 = {0.f, 0.f, 0.f, 0.f};
    c0 = mfma16(qf0, *(const bf16x8*)(&Ks[r16][kof]), c0);
    c0 = mfma16(qf1, *(const bf16x8*)(&Ks[r16][32 + kof]), c0);
    c1 = mfma16(qf0, *(const bf16x8*)(&Ks[16 + r16][kof]), c1);
    c1 = mfma16(qf1, *(const bf16x8*)(&Ks[16 + r16][32 + kof]), c1);

    // causal mask: C layout row=(lane>>4)*4+r (q), col=lane&15 (kv)
    const int qrow0 = q0 + (lane >> 4) * 4;
    const int kvc = kvbase + r16;
#pragma unroll
    for (int r = 0; r < 4; ++r) {
      if (kvc > qrow0 + r) c0[r] = -1e30f;
      if (kvc + 16 > qrow0 + r) c1[r] = -1e30f;
    }

    // row max across the 16 lanes holding this row
    float pm[4];
#pragma unroll
    for (int r = 0; r < 4; ++r) pm[r] = fmaxf(c0[r], c1[r]);
#pragma unroll
    for (int off = 1; off < 16; off <<= 1)
#pragma unroll
      for (int r = 0; r < 4; ++r) pm[r] = fmaxf(pm[r], __shfl_xor(pm[r], off, 64));

    float alpha[4], rs[4];
    f32x4 p0, p1;
#pragma unroll
    for (int r = 0; r < 4; ++r) {
      float mn = fmaxf(m_r[r], pm[r]);
      alpha[r] = __expf(m_r[r] - mn);
      m_r[r] = mn;
      p0[r] = __expf(c0[r] - mn);
      p1[r] = __expf(c1[r] - mn);
      rs[r] = p0[r] + p1[r];
    }
#pragma unroll
    for (int off = 1; off < 16; off <<= 1)
#pragma unroll
      for (int r = 0; r < 4; ++r) rs[r] += __shfl_xor(rs[r], off, 64);
#pragma unroll
    for (int r = 0; r < 4; ++r) l_r[r] = l_r[r] * alpha[r] + rs[r];
#pragma unroll
    for (int n = 0; n < 4; ++n)
#pragma unroll
      for (int r = 0; r < 4; ++r) acc[n][r] *= alpha[r];

    // P (C layout) -> LDS -> A-fragment layout
#pragma unroll
    for (int r = 0; r < 4; ++r) {
      Ps[wid][(lane >> 4) * 4 + r][r16]      = __float2bfloat16(p0[r]);
      Ps[wid][(lane >> 4) * 4 + r][16 + r16] = __float2bfloat16(p1[r]);
    }
    bf16x8 pf = *(const bf16x8*)(&Ps[wid][r16][kof]);
#pragma unroll
    for (int n = 0; n < 4; ++n)
      acc[n] = mfma16(pf, *(const bf16x8*)(&Vt[n * 16 + r16][kof]), acc[n]);
  }

  // epilogue: ctx[s, h*64+d] = acc / l
#pragma unroll
  for (int n = 0; n < 4; ++n)
#pragma unroll
    for (int r = 0; r < 4; ++r) {
      int row = q0 + (lane >> 4) * 4 + r;
      int col = h * HD + n * 16 + r16;
      ctx[(long)row * DMODEL + col] = __float2bfloat16(acc[n][r] / l_r[r]);
    }
}

extern "C" void kernel_launch(void* const* d_in, const int* in_sizes, int n_in,
                              void* d_out, int out_size, void* d_ws, size_t ws_size,
                              hipStream_t stream) {
  (void)in_sizes; (void)n_in; (void)out_size; (void)ws_size;
  const float* x  = (const float*)d_in[0];
  const float* Wq = (const float*)d_in[1];
  const float* Wk = (const float*)d_in[2];
  const float* Wv = (const float*)d_in[3];
  const float* Wo = (const float*)d_in[4];
  const float* bo = (const float*)d_in[5];
  float* out = (float*)d_out;

  char* ws = (char*)d_ws;
  bf16* xb   = (bf16*)(ws);                   //  8 MB: x in bf16 [4096,1024]
  bf16* wqkv = (bf16*)(ws + 8388608);         //  6 MB: packed Wq;Wk;Wv [3072,1024]
  bf16* wob  = (bf16*)(ws + 14680064);        //  2 MB: Wo [1024,1024]
  bf16* qkvb = (bf16*)(ws + 16777216);        // 24 MB: QKV [4096,3072]
  bf16* ctxb = (bf16*)(ws + 41943040);        //  8 MB: ctx [4096,1024]

  cvt_kernel<<<dim3(4096), dim3(256), 0, stream>>>(x, xb, 4194304);
  cvt_kernel<<<dim3(1024), dim3(256), 0, stream>>>(Wq, wqkv, 1048576);
  cvt_kernel<<<dim3(1024), dim3(256), 0, stream>>>(Wk, wqkv + 1048576, 1048576);
  cvt_kernel<<<dim3(1024), dim3(256), 0, stream>>>(Wv, wqkv + 2097152, 1048576);
  cvt_kernel<<<dim3(1024), dim3(256), 0, stream>>>(Wo, wob, 1048576);

  gemm_bt<1><<<dim3(24, 32), dim3(256), 0, stream>>>(xb, wqkv, (void*)qkvb, nullptr,
                                                     4096, 3072, 1024);
  rope_kernel<<<dim3(16384), dim3(256), 0, stream>>>(qkvb);
  attn_kernel<<<dim3(64, 16), dim3(256), 0, stream>>>(qkvb, ctxb);
  gemm_bt<0><<<dim3(8, 32), dim3(256), 0, stream>>>(ctxb, wob, (void*)out, bo,
                                                    4096, 1024, 1024);
}

// Round 3
// 311.523 us; speedup vs baseline: 1.4117x; 1.4117x over previous
//
#include <hip/hip_runtime.h>
#include <hip/hip_bf16.h>

typedef __hip_bfloat16 bf16;
typedef unsigned short u16;
typedef float f32x4 __attribute__((ext_vector_type(4)));
typedef __bf16 bf16x8 __attribute__((ext_vector_type(8)));
typedef u16 u16x8 __attribute__((ext_vector_type(8)));

#define DMODEL 1024
#define NH 16
#define HD 64
#define QKV_LD 3072

typedef __attribute__((address_space(1))) const void* as1_cvp;
typedef __attribute__((address_space(3))) void* as3_vp;

__device__ __forceinline__ void gload_lds16(const void* g, void* l) {
  __builtin_amdgcn_global_load_lds((as1_cvp)g, (as3_vp)l, 16, 0, 0);
}

__device__ __forceinline__ f32x4 mfma16(bf16x8 a, bf16x8 b, f32x4 c) {
  return __builtin_amdgcn_mfma_f32_16x16x32_bf16(a, b, c, 0, 0, 0);
}

// ---------------- fp32 -> bf16 conversion, 4 elems/thread ----------------
__global__ __launch_bounds__(256) void cvt_kernel(const float* __restrict__ src,
                                                  bf16* __restrict__ dst, int n) {
  int i = (blockIdx.x * 256 + threadIdx.x) * 4;
  if (i >= n) return;
  float4 v = *(const float4*)(src + i);
  union { ushort4 u; bf16 h[4]; } o;
  o.h[0] = __float2bfloat16(v.x);
  o.h[1] = __float2bfloat16(v.y);
  o.h[2] = __float2bfloat16(v.z);
  o.h[3] = __float2bfloat16(v.w);
  *(ushort4*)(dst + i) = o.u;
}

// ---------------- RoPE on Q and K regions of QKV, in place ----------------
// Also folds the 1/sqrt(HD)=0.125 score scale into Q (exact in bf16).
__global__ __launch_bounds__(256) void rope_kernel(bf16* __restrict__ qkv) {
  int idx = blockIdx.x * 256 + threadIdx.x;   // 4096 rows * 2 regions * 512 pairs
  int p = idx & 511;          // pair within row-region
  int s = (idx >> 9) & 4095;  // sequence position
  int region = idx >> 21;     // 0 = Q, 1 = K
  int i = p & 31;             // pair index within head
  int h = p >> 5;             // head
  long base = (long)s * QKV_LD + region * DMODEL + h * HD + 2 * i;
  float x1 = __bfloat162float(qkv[base]);
  float x2 = __bfloat162float(qkv[base + 1]);
  float invf = powf(10000.0f, -(float)(2 * i) / 64.0f);
  float ang = (float)s * invf;
  float sn, cs;
  sincosf(ang, &sn, &cs);
  float scale = (region == 0) ? 0.125f : 1.0f;
  float r1 = (x1 * cs - x2 * sn) * scale;
  float r2 = (x1 * sn + x2 * cs) * scale;
  qkv[base]     = __float2bfloat16(r1);
  qkv[base + 1] = __float2bfloat16(r2);
}

// ---------------- NT GEMM: C[M,N] = A[M,K] * B[N,K]^T ----------------
// 128x128 tile, BK=32, 4 waves (2x2), 16x16x32 bf16 MFMA, global_load_lds staging.
template <int OUT_BF16>
__global__ __launch_bounds__(256) void gemm_bt(const bf16* __restrict__ A,
                                               const bf16* __restrict__ B,
                                               void* __restrict__ Cout,
                                               const float* __restrict__ bias,
                                               int M, int N, int K) {
  __shared__ __align__(16) bf16 As[128 * 32];
  __shared__ __align__(16) bf16 Bs[128 * 32];
  const int tid = threadIdx.x;
  const int lane = tid & 63;
  const int wid = tid >> 6;
  const int brow = blockIdx.y * 128;
  const int bcol = blockIdx.x * 128;
  const int wr = wid >> 1, wc = wid & 1;

  f32x4 acc[4][4] = {};

  const int srow = lane >> 2;        // 0..15
  const int scol = (lane & 3) * 8;   // 0,8,16,24
  const bf16* Ag = A + (long)(brow + wid * 32 + srow) * K + scol;
  const bf16* Bg = B + (long)(bcol + wid * 32 + srow) * K + scol;
  bf16* AsW = As + wid * 32 * 32;    // wave-uniform LDS base (linear dest)
  bf16* BsW = Bs + wid * 32 * 32;
  const int kof = (lane >> 4) * 8;
  const int r16 = lane & 15;

  for (int k0 = 0; k0 < K; k0 += 32) {
    __syncthreads();
    gload_lds16(Ag + k0, AsW);
    gload_lds16(Ag + k0 + (long)16 * K, AsW + 16 * 32);
    gload_lds16(Bg + k0, BsW);
    gload_lds16(Bg + k0 + (long)16 * K, BsW + 16 * 32);
    __syncthreads();
    bf16x8 af[4], bfr[4];
#pragma unroll
    for (int m = 0; m < 4; ++m)
      af[m] = *(const bf16x8*)(As + (wr * 64 + m * 16 + r16) * 32 + kof);
#pragma unroll
    for (int n = 0; n < 4; ++n)
      bfr[n] = *(const bf16x8*)(Bs + (wc * 64 + n * 16 + r16) * 32 + kof);
#pragma unroll
    for (int m = 0; m < 4; ++m)
#pragma unroll
      for (int n = 0; n < 4; ++n)
        acc[m][n] = mfma16(af[m], bfr[n], acc[m][n]);
  }

  const int r0 = (lane >> 4) * 4;
#pragma unroll
  for (int m = 0; m < 4; ++m) {
#pragma unroll
    for (int n = 0; n < 4; ++n) {
      int row = brow + wr * 64 + m * 16 + r0;
      int col = bcol + wc * 64 + n * 16 + r16;
#pragma unroll
      for (int r = 0; r < 4; ++r) {
        if (OUT_BF16) {
          ((bf16*)Cout)[(long)(row + r) * N + col] = __float2bfloat16(acc[m][n][r]);
        } else {
          ((float*)Cout)[(long)(row + r) * N + col] = acc[m][n][r] + bias[col];
        }
      }
    }
  }
}

// ---------------- causal flash attention (v2) ----------------
// grid (64 qblocks desc, 16 heads), 256 threads = 4 waves; wave owns 16 q rows.
// KVBLK=64, double-buffered LDS, ONE barrier per iteration, staged loads
// issued right after the barrier and written to the other buffer at the end.
// K in LDS [64][72] (144B stride -> 2-way banks, 16B aligned). V transposed
// [64][72]. P staged per-wave through padded LDS.
__global__ __launch_bounds__(256) void attn_kernel(const bf16* __restrict__ qkv,
                                                   bf16* __restrict__ ctx) {
  __shared__ __align__(16) bf16 Ks[2][64][72];
  __shared__ __align__(16) bf16 Vt[2][64][72];
  __shared__ __align__(16) bf16 Ps[4][16][72];

  const int tid = threadIdx.x;
  const int lane = tid & 63;
  const int wid = tid >> 6;
  const int h = blockIdx.y;
  const int qblk = 63 - blockIdx.x;       // heavy blocks launch first
  const int q0 = qblk * 64 + wid * 16;
  const int r16 = lane & 15;
  const int g = lane >> 4;
  const int kof = g * 8;
  const long qcol = (long)h * HD;
  const long kcol = DMODEL + h * HD;
  const long vcol = 2 * DMODEL + h * HD;
  const u16* qkv16 = (const u16*)qkv;

  // Q fragments (0.125 scale folded in by rope_kernel)
  bf16x8 qf0 = *(const bf16x8*)(qkv + (long)(q0 + r16) * QKV_LD + qcol + kof);
  bf16x8 qf1 = *(const bf16x8*)(qkv + (long)(q0 + r16) * QKV_LD + qcol + 32 + kof);

  float m_r[4], l_r[4];
  f32x4 acc[4] = {};
#pragma unroll
  for (int r = 0; r < 4; ++r) { m_r[r] = -1e30f; l_r[r] = 0.0f; }

  // staging geometry
  const int skr = tid >> 2;               // K row 0..63
  const int skc = (tid & 3) * 16;         // K col base (elems)
  const int svk = wid * 16;               // V k-range base (d = lane)

  const int nkb = qblk + 1;               // 64-row KV blocks
  u16x8 krA, krB, vrA, vrB;

  // prologue: load + write block 0 into buf 0
  {
    const u16* kp = qkv16 + (long)skr * QKV_LD + kcol + skc;
    krA = *(const u16x8*)kp;
    krB = *(const u16x8*)(kp + 8);
    const u16* vp = qkv16 + (long)svk * QKV_LD + vcol + lane;
#pragma unroll
    for (int j = 0; j < 8; ++j) vrA[j] = vp[(long)j * QKV_LD];
#pragma unroll
    for (int j = 0; j < 8; ++j) vrB[j] = vp[(long)(8 + j) * QKV_LD];
    *(u16x8*)(&Ks[0][skr][skc]) = krA;
    *(u16x8*)(&Ks[0][skr][skc + 8]) = krB;
    *(u16x8*)(&Vt[0][lane][svk]) = vrA;
    *(u16x8*)(&Vt[0][lane][svk + 8]) = vrB;
  }

  for (int kb = 0; kb < nkb; ++kb) {
    const int cur = kb & 1;
    const int kv0 = kb * 64;
    const bool last = (kb + 1 == nkb);
    __syncthreads();   // staging of block kb visible; prev iter reads done

    // issue next block's global loads into regs (latency hides under compute)
    if (!last) {
      const long kv1 = (long)(kb + 1) * 64;
      const u16* kp = qkv16 + (kv1 + skr) * QKV_LD + kcol + skc;
      krA = *(const u16x8*)kp;
      krB = *(const u16x8*)(kp + 8);
      const u16* vp = qkv16 + (kv1 + svk) * QKV_LD + vcol + lane;
#pragma unroll
      for (int j = 0; j < 8; ++j) vrA[j] = vp[(long)j * QKV_LD];
#pragma unroll
      for (int j = 0; j < 8; ++j) vrB[j] = vp[(long)(8 + j) * QKV_LD];
    }

    // S = Q K^T : 4 col-fragments of 16 kv each, K-dim 64 in 2 halves
    f32x4 c[4];
#pragma unroll
    for (int f = 0; f < 4; ++f) {
      f32x4 z = {0.f, 0.f, 0.f, 0.f};
      z = mfma16(qf0, *(const bf16x8*)(&Ks[cur][f * 16 + r16][kof]), z);
      z = mfma16(qf1, *(const bf16x8*)(&Ks[cur][f * 16 + r16][32 + kof]), z);
      c[f] = z;
    }

    // causal mask on the diagonal block only
    if (last) {
      const int qrow0 = q0 + g * 4;
#pragma unroll
      for (int f = 0; f < 4; ++f) {
        const int kvc = kv0 + f * 16 + r16;
#pragma unroll
        for (int r = 0; r < 4; ++r)
          if (kvc > qrow0 + r) c[f][r] = -1e30f;
      }
    }

    // online softmax (rows live across 16 lanes sharing g)
    float pm[4];
#pragma unroll
    for (int r = 0; r < 4; ++r)
      pm[r] = fmaxf(fmaxf(c[0][r], c[1][r]), fmaxf(c[2][r], c[3][r]));
#pragma unroll
    for (int off = 1; off < 16; off <<= 1)
#pragma unroll
      for (int r = 0; r < 4; ++r) pm[r] = fmaxf(pm[r], __shfl_xor(pm[r], off, 64));

    float alpha[4], rs[4];
    f32x4 p[4];
#pragma unroll
    for (int r = 0; r < 4; ++r) {
      float mn = fmaxf(m_r[r], pm[r]);
      alpha[r] = __expf(m_r[r] - mn);
      m_r[r] = mn;
#pragma unroll
      for (int f = 0; f < 4; ++f) p[f][r] = __expf(c[f][r] - mn);
      rs[r] = (p[0][r] + p[1][r]) + (p[2][r] + p[3][r]);
    }
#pragma unroll
    for (int off = 1; off < 16; off <<= 1)
#pragma unroll
      for (int r = 0; r < 4; ++r) rs[r] += __shfl_xor(rs[r], off, 64);
#pragma unroll
    for (int r = 0; r < 4; ++r) l_r[r] = l_r[r] * alpha[r] + rs[r];
#pragma unroll
    for (int n = 0; n < 4; ++n)
#pragma unroll
      for (int r = 0; r < 4; ++r) acc[n][r] *= alpha[r];

    // P (C layout) -> per-wave LDS -> A-fragment layout
#pragma unroll
    for (int f = 0; f < 4; ++f)
#pragma unroll
      for (int r = 0; r < 4; ++r)
        Ps[wid][g * 4 + r][f * 16 + r16] = __float2bfloat16(p[f][r]);

    bf16x8 pf0 = *(const bf16x8*)(&Ps[wid][r16][kof]);
    bf16x8 pf1 = *(const bf16x8*)(&Ps[wid][r16][32 + kof]);
#pragma unroll
    for (int n = 0; n < 4; ++n) {
      acc[n] = mfma16(pf0, *(const bf16x8*)(&Vt[cur][n * 16 + r16][kof]), acc[n]);
      acc[n] = mfma16(pf1, *(const bf16x8*)(&Vt[cur][n * 16 + r16][32 + kof]), acc[n]);
    }

    // write staged regs into the other buffer (safe after this iter's barrier)
    if (!last) {
      const int nb = cur ^ 1;
      *(u16x8*)(&Ks[nb][skr][skc]) = krA;
      *(u16x8*)(&Ks[nb][skr][skc + 8]) = krB;
      *(u16x8*)(&Vt[nb][lane][svk]) = vrA;
      *(u16x8*)(&Vt[nb][lane][svk + 8]) = vrB;
    }
  }

  // epilogue: ctx[s, h*64+d] = acc / l
#pragma unroll
  for (int n = 0; n < 4; ++n)
#pragma unroll
    for (int r = 0; r < 4; ++r) {
      int row = q0 + g * 4 + r;
      int col = h * HD + n * 16 + r16;
      ctx[(long)row * DMODEL + col] = __float2bfloat16(acc[n][r] / l_r[r]);
    }
}

extern "C" void kernel_launch(void* const* d_in, const int* in_sizes, int n_in,
                              void* d_out, int out_size, void* d_ws, size_t ws_size,
                              hipStream_t stream) {
  (void)in_sizes; (void)n_in; (void)out_size; (void)ws_size;
  const float* x  = (const float*)d_in[0];
  const float* Wq = (const float*)d_in[1];
  const float* Wk = (const float*)d_in[2];
  const float* Wv = (const float*)d_in[3];
  const float* Wo = (const float*)d_in[4];
  const float* bo = (const float*)d_in[5];
  float* out = (float*)d_out;

  char* ws = (char*)d_ws;
  bf16* xb   = (bf16*)(ws);                   //  8 MB: x in bf16 [4096,1024]
  bf16* wqkv = (bf16*)(ws + 8388608);         //  6 MB: packed Wq;Wk;Wv [3072,1024]
  bf16* wob  = (bf16*)(ws + 14680064);        //  2 MB: Wo [1024,1024]
  bf16* qkvb = (bf16*)(ws + 16777216);        // 24 MB: QKV [4096,3072]
  bf16* ctxb = (bf16*)(ws + 41943040);        //  8 MB: ctx [4096,1024]

  cvt_kernel<<<dim3(4096), dim3(256), 0, stream>>>(x, xb, 4194304);
  cvt_kernel<<<dim3(1024), dim3(256), 0, stream>>>(Wq, wqkv, 1048576);
  cvt_kernel<<<dim3(1024), dim3(256), 0, stream>>>(Wk, wqkv + 1048576, 1048576);
  cvt_kernel<<<dim3(1024), dim3(256), 0, stream>>>(Wv, wqkv + 2097152, 1048576);
  cvt_kernel<<<dim3(1024), dim3(256), 0, stream>>>(Wo, wob, 1048576);

  gemm_bt<1><<<dim3(24, 32), dim3(256), 0, stream>>>(xb, wqkv, (void*)qkvb, nullptr,
                                                     4096, 3072, 1024);
  rope_kernel<<<dim3(16384), dim3(256), 0, stream>>>(qkvb);
  attn_kernel<<<dim3(64, 16), dim3(256), 0, stream>>>(qkvb, ctxb);
  gemm_bt<0><<<dim3(8, 32), dim3(256), 0, stream>>>(ctxb, wob, (void*)out, bo,
                                                    4096, 1024, 1024);
}

// Round 5
// 249.087 us; speedup vs baseline: 1.7656x; 1.2507x over previous
//
#include <hip/hip_runtime.h>
#include <hip/hip_bf16.h>

typedef __hip_bfloat16 bf16;
typedef unsigned short u16;
typedef unsigned int u32;
typedef float f32x4 __attribute__((ext_vector_type(4)));
typedef float f32x16 __attribute__((ext_vector_type(16)));
typedef __bf16 bf16x8 __attribute__((ext_vector_type(8)));
typedef u16 u16x8 __attribute__((ext_vector_type(8)));

#define DMODEL 1024
#define NH 16
#define HD 64
#define QKV_LD 3072

typedef __attribute__((address_space(1))) const void* as1_cvp;
typedef __attribute__((address_space(3))) void* as3_vp;

__device__ __forceinline__ void gload_lds16(const void* g, void* l) {
  __builtin_amdgcn_global_load_lds((as1_cvp)g, (as3_vp)l, 16, 0, 0);
}

__device__ __forceinline__ f32x4 mfma16(bf16x8 a, bf16x8 b, f32x4 c) {
  return __builtin_amdgcn_mfma_f32_16x16x32_bf16(a, b, c, 0, 0, 0);
}
__device__ __forceinline__ f32x16 mfma32(bf16x8 a, bf16x8 b, f32x16 c) {
  return __builtin_amdgcn_mfma_f32_32x32x16_bf16(a, b, c, 0, 0, 0);
}

__device__ __forceinline__ u16 f2b(float f) {
  union { bf16 b; u16 s; } u; u.b = __float2bfloat16(f); return u.s;
}
__device__ __forceinline__ u32 pkbf(float a, float b) {
  union { __hip_bfloat162 h; u32 u; } cv;
  cv.h = __float22bfloat162_rn(make_float2(a, b));
  return cv.u;
}

// ---------------- fp32 -> bf16 conversion, 4 elems/thread ----------------
__global__ __launch_bounds__(256) void cvt_kernel(const float* __restrict__ src,
                                                  bf16* __restrict__ dst, int n) {
  int i = (blockIdx.x * 256 + threadIdx.x) * 4;
  if (i >= n) return;
  float4 v = *(const float4*)(src + i);
  union { ushort4 u; bf16 h[4]; } o;
  o.h[0] = __float2bfloat16(v.x);
  o.h[1] = __float2bfloat16(v.y);
  o.h[2] = __float2bfloat16(v.z);
  o.h[3] = __float2bfloat16(v.w);
  *(ushort4*)(dst + i) = o.u;
}

// ---------------- RoPE on Q and K regions of QKV, in place ----------------
__global__ __launch_bounds__(256) void rope_kernel(bf16* __restrict__ qkv) {
  int idx = blockIdx.x * 256 + threadIdx.x;
  int p = idx & 511;
  int s = (idx >> 9) & 4095;
  int region = idx >> 21;
  int i = p & 31;
  int h = p >> 5;
  long base = (long)s * QKV_LD + region * DMODEL + h * HD + 2 * i;
  float x1 = __bfloat162float(qkv[base]);
  float x2 = __bfloat162float(qkv[base + 1]);
  float invf = powf(10000.0f, -(float)(2 * i) / 64.0f);
  float ang = (float)s * invf;
  float sn, cs;
  sincosf(ang, &sn, &cs);
  float scale = (region == 0) ? 0.125f : 1.0f;
  float r1 = (x1 * cs - x2 * sn) * scale;
  float r2 = (x1 * sn + x2 * cs) * scale;
  qkv[base]     = __float2bfloat16(r1);
  qkv[base + 1] = __float2bfloat16(r2);
}

// ---------------- NT GEMM (unchanged) ----------------
template <int OUT_BF16>
__global__ __launch_bounds__(256) void gemm_bt(const bf16* __restrict__ A,
                                               const bf16* __restrict__ B,
                                               void* __restrict__ Cout,
                                               const float* __restrict__ bias,
                                               int M, int N, int K) {
  __shared__ __align__(16) bf16 As[128 * 32];
  __shared__ __align__(16) bf16 Bs[128 * 32];
  const int tid = threadIdx.x;
  const int lane = tid & 63;
  const int wid = tid >> 6;
  const int brow = blockIdx.y * 128;
  const int bcol = blockIdx.x * 128;
  const int wr = wid >> 1, wc = wid & 1;

  f32x4 acc[4][4] = {};

  const int srow = lane >> 2;
  const int scol = (lane & 3) * 8;
  const bf16* Ag = A + (long)(brow + wid * 32 + srow) * K + scol;
  const bf16* Bg = B + (long)(bcol + wid * 32 + srow) * K + scol;
  bf16* AsW = As + wid * 32 * 32;
  bf16* BsW = Bs + wid * 32 * 32;
  const int kof = (lane >> 4) * 8;
  const int r16 = lane & 15;

  for (int k0 = 0; k0 < K; k0 += 32) {
    __syncthreads();
    gload_lds16(Ag + k0, AsW);
    gload_lds16(Ag + k0 + (long)16 * K, AsW + 16 * 32);
    gload_lds16(Bg + k0, BsW);
    gload_lds16(Bg + k0 + (long)16 * K, BsW + 16 * 32);
    __syncthreads();
    bf16x8 af[4], bfr[4];
#pragma unroll
    for (int m = 0; m < 4; ++m)
      af[m] = *(const bf16x8*)(As + (wr * 64 + m * 16 + r16) * 32 + kof);
#pragma unroll
    for (int n = 0; n < 4; ++n)
      bfr[n] = *(const bf16x8*)(Bs + (wc * 64 + n * 16 + r16) * 32 + kof);
#pragma unroll
    for (int m = 0; m < 4; ++m)
#pragma unroll
      for (int n = 0; n < 4; ++n)
        acc[m][n] = mfma16(af[m], bfr[n], acc[m][n]);
  }

  const int r0 = (lane >> 4) * 4;
#pragma unroll
  for (int m = 0; m < 4; ++m) {
#pragma unroll
    for (int n = 0; n < 4; ++n) {
      int row = brow + wr * 64 + m * 16 + r0;
      int col = bcol + wc * 64 + n * 16 + r16;
#pragma unroll
      for (int r = 0; r < 4; ++r) {
        if (OUT_BF16) {
          ((bf16*)Cout)[(long)(row + r) * N + col] = __float2bfloat16(acc[m][n][r]);
        } else {
          ((float*)Cout)[(long)(row + r) * N + col] = acc[m][n][r] + bias[col];
        }
      }
    }
  }
}

// ---------------- causal flash attention (v4: swapped-operand, 32x32) -------
// grid (32 qblocks desc, 16 heads), 256 thr = 4 waves; wave owns 32 q rows.
// S^T = mfma32(K, Q^T): lane owns q = lane&31 -> softmax state per-lane scalar.
// Lane-pair (l, l^32) exchanges via __shfl_xor(.,32) (known-correct semantics).
// O^T = mfma32(V^T, P^T): alpha-rescale & 1/l are per-lane scalars.
// K staged by global_load_lds with pre-swizzled source; V reg-gathered,
// both stored with slot^=(row&7) XOR swizzle.
__global__ __launch_bounds__(256, 4) void attn_kernel(const bf16* __restrict__ qkv,
                                                      bf16* __restrict__ ctx) {
  __shared__ __align__(16) bf16 smem[16384];   // 32 KB
  bf16 (*Ks)[64][64] = (bf16(*)[64][64])(smem);          // 2 bufs, [kv][d]
  bf16 (*Vt)[64][64] = (bf16(*)[64][64])(smem + 8192);   // 2 bufs, [d][kv]

  const int tid = threadIdx.x;
  const int lane = tid & 63;
  const int wid = tid >> 6;
  const int hi = lane >> 5;
  const int l31 = lane & 31;
  const int h = blockIdx.y;
  const int qblk = 31 - blockIdx.x;          // heavy blocks first
  const int q0w = qblk * 128 + wid * 32;     // wave's q base
  const long kcol = DMODEL + (long)h * HD;
  const long vcol = 2 * DMODEL + (long)h * HD;
  const u16* qkv16 = (const u16*)qkv;

  // Q B-fragments: lane holds Q[q=l31][d = kt*16 + hi*8 .. +8]
  bf16x8 qf[4];
  {
    const bf16* qp = qkv + (long)(q0w + l31) * QKV_LD + h * HD + hi * 8;
#pragma unroll
    for (int kt = 0; kt < 4; ++kt) qf[kt] = *(const bf16x8*)(qp + kt * 16);
  }

  const int kOff = ((lane & 7) ^ (lane >> 3)) * 8;  // pre-swizzled K src offset
  const int krow0 = wid * 16 + (lane >> 3);         // rows this lane stages (base)

  f32x16 acc[2] = {};
  float m_r = -1e30f, l_r = 0.0f;

  const int nkb = 2 * qblk + 2;
  u16x8 va, vb;

  // prologue: stage block 0 into buf 0
  {
#pragma unroll
    for (int c = 0; c < 2; ++c)
      gload_lds16(qkv + (long)(krow0 + c * 8) * QKV_LD + kcol + kOff,
                  &Ks[0][wid * 16 + c * 8][0]);
    const u16* vp = qkv16 + (long)(wid * 16) * QKV_LD + vcol + lane;
#pragma unroll
    for (int j = 0; j < 8; ++j) va[j] = vp[(long)j * QKV_LD];
#pragma unroll
    for (int j = 0; j < 8; ++j) vb[j] = vp[(long)(8 + j) * QKV_LD];
    *(u16x8*)(&Vt[0][lane][((wid * 2) ^ (lane & 7)) * 8]) = va;
    *(u16x8*)(&Vt[0][lane][((wid * 2 + 1) ^ (lane & 7)) * 8]) = vb;
  }

  for (int kb = 0; kb < nkb; ++kb) {
    const int cur = kb & 1;
    const int kv0 = kb * 64;
    const bool pre = (kb + 1 < nkb);
    __syncthreads();

    // prefetch next tile: K -> LDS (other buf) async, V -> regs
    if (pre) {
      const long kvn = kv0 + 64;
#pragma unroll
      for (int c = 0; c < 2; ++c)
        gload_lds16(qkv + (kvn + krow0 + c * 8) * QKV_LD + kcol + kOff,
                    &Ks[cur ^ 1][wid * 16 + c * 8][0]);
      const u16* vp = qkv16 + (kvn + wid * 16) * QKV_LD + vcol + lane;
#pragma unroll
      for (int j = 0; j < 8; ++j) va[j] = vp[(long)j * QKV_LD];
#pragma unroll
      for (int j = 0; j < 8; ++j) vb[j] = vp[(long)(8 + j) * QKV_LD];
    }

#pragma unroll
    for (int sub = 0; sub < 2; ++sub) {
      const int kvs = kv0 + sub * 32;
      if (kvs > q0w + 31) continue;          // fully masked for this wave (uniform)
      const int krow = sub * 32 + l31;

      // S^T = K * Q^T over d=64 (4 mfma of k=16)
      f32x16 c16 = {};
#pragma unroll
      for (int kt = 0; kt < 4; ++kt) {
        bf16x8 kf = *(const bf16x8*)(&Ks[cur][krow][(((kt << 1) | hi) ^ (krow & 7)) * 8]);
        c16 = mfma32(kf, qf[kt], c16);
      }

      // causal mask (diagonal region only)
      if (kvs + 31 > q0w) {
        const int q = q0w + l31;
        const int kvb = kvs + 4 * hi;
#pragma unroll
        for (int r = 0; r < 16; ++r) {
          int kv = kvb + (r & 3) + 8 * (r >> 2);
          if (kv > q) c16[r] = -1e30f;
        }
      }

      // per-lane online softmax (q = l31); pair (l, l^32) holds the 32 kv
      float t0 = fmaxf(fmaxf(c16[0], c16[1]), fmaxf(c16[2], c16[3]));
      float t1 = fmaxf(fmaxf(c16[4], c16[5]), fmaxf(c16[6], c16[7]));
      float t2 = fmaxf(fmaxf(c16[8], c16[9]), fmaxf(c16[10], c16[11]));
      float t3 = fmaxf(fmaxf(c16[12], c16[13]), fmaxf(c16[14], c16[15]));
      float pmax = fmaxf(fmaxf(t0, t1), fmaxf(t2, t3));
      pmax = fmaxf(pmax, __shfl_xor(pmax, 32, 64));

      if (!__all(pmax <= m_r + 8.0f)) {      // defer-max (T13)
        float mn = fmaxf(m_r, pmax);
        float al = __expf(m_r - mn);
        m_r = mn;
        l_r *= al;
#pragma unroll
        for (int dt = 0; dt < 2; ++dt)
#pragma unroll
          for (int r = 0; r < 16; ++r) acc[dt][r] *= al;
      }

      float p[16];
#pragma unroll
      for (int r = 0; r < 16; ++r) p[r] = __expf(c16[r] - m_r);
      float rs = ((p[0] + p[1]) + (p[2] + p[3])) + ((p[4] + p[5]) + (p[6] + p[7])) +
                 (((p[8] + p[9]) + (p[10] + p[11])) + ((p[12] + p[13]) + (p[14] + p[15])));
      rs += __shfl_xor(rs, 32, 64);
      l_r += rs;

      // P^T -> B-fragments: pack pairs to bf16x2 words, exchange across l^32.
      // Lane (hi=0) holds kv rows {0-3,8-11,16-19,24-27}; partner the rest.
      union BP { u32 u[4]; bf16x8 v; } f0, f1;
      {
        u32 x01 = pkbf(p[0], p[1]), x23 = pkbf(p[2], p[3]);   // rows 0,1 / 2,3 (+4*hi)
        u32 x45 = pkbf(p[4], p[5]), x67 = pkbf(p[6], p[7]);   // rows 8,9 / 10,11 (+4*hi)
        u32 s01 = __shfl_xor(x01, 32, 64), s23 = __shfl_xor(x23, 32, 64);
        u32 s45 = __shfl_xor(x45, 32, 64), s67 = __shfl_xor(x67, 32, 64);
        f0.u[0] = hi ? s45 : x01;   // k=0,1  : rows 0,1 (hi=0) / 8,9  (hi=1)
        f0.u[1] = hi ? s67 : x23;   // k=2,3  : rows 2,3 / 10,11
        f0.u[2] = hi ? x45 : s01;   // k=4,5  : rows 4,5 / 12,13
        f0.u[3] = hi ? x67 : s23;   // k=6,7  : rows 6,7 / 14,15
      }
      {
        u32 x01 = pkbf(p[8], p[9]), x23 = pkbf(p[10], p[11]);
        u32 x45 = pkbf(p[12], p[13]), x67 = pkbf(p[14], p[15]);
        u32 s01 = __shfl_xor(x01, 32, 64), s23 = __shfl_xor(x23, 32, 64);
        u32 s45 = __shfl_xor(x45, 32, 64), s67 = __shfl_xor(x67, 32, 64);
        f1.u[0] = hi ? s45 : x01;
        f1.u[1] = hi ? s67 : x23;
        f1.u[2] = hi ? x45 : s01;
        f1.u[3] = hi ? x67 : s23;
      }

      // O^T += V^T * P^T
#pragma unroll
      for (int dt = 0; dt < 2; ++dt) {
        const int vrow = dt * 32 + l31;
        bf16x8 vf0 = *(const bf16x8*)(&Vt[cur][vrow][(((sub << 2) | hi) ^ (vrow & 7)) * 8]);
        acc[dt] = mfma32(vf0, f0.v, acc[dt]);
        bf16x8 vf1 = *(const bf16x8*)(&Vt[cur][vrow][(((sub << 2) | 2 | hi) ^ (vrow & 7)) * 8]);
        acc[dt] = mfma32(vf1, f1.v, acc[dt]);
      }
    }

    // write staged V regs into the other buffer
    if (pre) {
      const int nb = cur ^ 1;
      *(u16x8*)(&Vt[nb][lane][((wid * 2) ^ (lane & 7)) * 8]) = va;
      *(u16x8*)(&Vt[nb][lane][((wid * 2 + 1) ^ (lane & 7)) * 8]) = vb;
    }
  }

  __syncthreads();   // all waves done with Ks/Vt; LDS reused for epilogue

  // epilogue: O^T regs -> per-wave LDS [32 q][68 d] -> coalesced ctx store
  bf16* scr = smem + wid * 2176;
  const float inv = 1.0f / l_r;
#pragma unroll
  for (int dt = 0; dt < 2; ++dt)
#pragma unroll
    for (int g2 = 0; g2 < 4; ++g2) {
      union { u16 hh[4]; unsigned long long q8; } pk4;
#pragma unroll
      for (int j = 0; j < 4; ++j) pk4.hh[j] = f2b(acc[dt][g2 * 4 + j] * inv);
      *(unsigned long long*)(scr + l31 * 68 + dt * 32 + g2 * 8 + 4 * hi) = pk4.q8;
    }
  __syncthreads();   // fence + barrier: writes ordered & visible before reads

  const int qe = lane >> 1, he = lane & 1;
  u16* cp = (u16*)ctx + (long)(q0w + qe) * DMODEL + h * HD + he * 32;
#pragma unroll
  for (int j = 0; j < 4; ++j) {
    u16x8 v = *(const u16x8*)(scr + qe * 68 + he * 32 + j * 8);
    *(u16x8*)(cp + j * 8) = v;
  }
}

extern "C" void kernel_launch(void* const* d_in, const int* in_sizes, int n_in,
                              void* d_out, int out_size, void* d_ws, size_t ws_size,
                              hipStream_t stream) {
  (void)in_sizes; (void)n_in; (void)out_size; (void)ws_size;
  const float* x  = (const float*)d_in[0];
  const float* Wq = (const float*)d_in[1];
  const float* Wk = (const float*)d_in[2];
  const float* Wv = (const float*)d_in[3];
  const float* Wo = (const float*)d_in[4];
  const float* bo = (const float*)d_in[5];
  float* out = (float*)d_out;

  char* ws = (char*)d_ws;
  bf16* xb   = (bf16*)(ws);                   //  8 MB: x in bf16 [4096,1024]
  bf16* wqkv = (bf16*)(ws + 8388608);         //  6 MB: packed Wq;Wk;Wv [3072,1024]
  bf16* wob  = (bf16*)(ws + 14680064);        //  2 MB: Wo [1024,1024]
  bf16* qkvb = (bf16*)(ws + 16777216);        // 24 MB: QKV [4096,3072]
  bf16* ctxb = (bf16*)(ws + 41943040);        //  8 MB: ctx [4096,1024]

  cvt_kernel<<<dim3(4096), dim3(256), 0, stream>>>(x, xb, 4194304);
  cvt_kernel<<<dim3(1024), dim3(256), 0, stream>>>(Wq, wqkv, 1048576);
  cvt_kernel<<<dim3(1024), dim3(256), 0, stream>>>(Wk, wqkv + 1048576, 1048576);
  cvt_kernel<<<dim3(1024), dim3(256), 0, stream>>>(Wv, wqkv + 2097152, 1048576);
  cvt_kernel<<<dim3(1024), dim3(256), 0, stream>>>(Wo, wob, 1048576);

  gemm_bt<1><<<dim3(24, 32), dim3(256), 0, stream>>>(xb, wqkv, (void*)qkvb, nullptr,
                                                     4096, 3072, 1024);
  rope_kernel<<<dim3(16384), dim3(256), 0, stream>>>(qkvb);
  attn_kernel<<<dim3(32, 16), dim3(256), 0, stream>>>(qkvb, ctxb);
  gemm_bt<0><<<dim3(8, 32), dim3(256), 0, stream>>>(ctxb, wob, (void*)out, bo,
                                                    4096, 1024, 1024);
}

// Round 6
// 214.750 us; speedup vs baseline: 2.0479x; 1.1599x over previous
//
#include <hip/hip_runtime.h>
#include <hip/hip_bf16.h>

typedef __hip_bfloat16 bf16;
typedef unsigned short u16;
typedef unsigned int u32;
typedef float f32x4 __attribute__((ext_vector_type(4)));
typedef float f32x16 __attribute__((ext_vector_type(16)));
typedef __bf16 bf16x8 __attribute__((ext_vector_type(8)));
typedef u16 u16x8 __attribute__((ext_vector_type(8)));

#define DMODEL 1024
#define NH 16
#define HD 64
#define QKV_LD 3072

typedef __attribute__((address_space(1))) const void* as1_cvp;
typedef __attribute__((address_space(3))) void* as3_vp;

__device__ __forceinline__ void gload_lds16(const void* g, void* l) {
  __builtin_amdgcn_global_load_lds((as1_cvp)g, (as3_vp)l, 16, 0, 0);
}

__device__ __forceinline__ f32x4 mfma16(bf16x8 a, bf16x8 b, f32x4 c) {
  return __builtin_amdgcn_mfma_f32_16x16x32_bf16(a, b, c, 0, 0, 0);
}
__device__ __forceinline__ f32x16 mfma32(bf16x8 a, bf16x8 b, f32x16 c) {
  return __builtin_amdgcn_mfma_f32_32x32x16_bf16(a, b, c, 0, 0, 0);
}

__device__ __forceinline__ u16 f2b(float f) {
  union { bf16 b; u16 s; } u; u.b = __float2bfloat16(f); return u.s;
}
__device__ __forceinline__ u32 pkbf(float a, float b) {
  union { __hip_bfloat162 h; u32 u; } cv;
  cv.h = __float22bfloat162_rn(make_float2(a, b));
  return cv.u;
}

// ---------------- fp32 -> bf16 conversion, 4 elems/thread ----------------
__global__ __launch_bounds__(256) void cvt_kernel(const float* __restrict__ src,
                                                  bf16* __restrict__ dst, int n) {
  int i = (blockIdx.x * 256 + threadIdx.x) * 4;
  if (i >= n) return;
  float4 v = *(const float4*)(src + i);
  union { ushort4 u; bf16 h[4]; } o;
  o.h[0] = __float2bfloat16(v.x);
  o.h[1] = __float2bfloat16(v.y);
  o.h[2] = __float2bfloat16(v.z);
  o.h[3] = __float2bfloat16(v.w);
  *(ushort4*)(dst + i) = o.u;
}

// ---------------- RoPE on Q and K regions of QKV, in place ----------------
__global__ __launch_bounds__(256) void rope_kernel(bf16* __restrict__ qkv) {
  int idx = blockIdx.x * 256 + threadIdx.x;
  int p = idx & 511;
  int s = (idx >> 9) & 4095;
  int region = idx >> 21;
  int i = p & 31;
  int h = p >> 5;
  long base = (long)s * QKV_LD + region * DMODEL + h * HD + 2 * i;
  float x1 = __bfloat162float(qkv[base]);
  float x2 = __bfloat162float(qkv[base + 1]);
  float invf = powf(10000.0f, -(float)(2 * i) / 64.0f);
  float ang = (float)s * invf;
  float sn, cs;
  sincosf(ang, &sn, &cs);
  float scale = (region == 0) ? 0.125f : 1.0f;
  float r1 = (x1 * cs - x2 * sn) * scale;
  float r2 = (x1 * sn + x2 * cs) * scale;
  qkv[base]     = __float2bfloat16(r1);
  qkv[base + 1] = __float2bfloat16(r2);
}

// ---------------- NT GEMM (unchanged) ----------------
template <int OUT_BF16>
__global__ __launch_bounds__(256) void gemm_bt(const bf16* __restrict__ A,
                                               const bf16* __restrict__ B,
                                               void* __restrict__ Cout,
                                               const float* __restrict__ bias,
                                               int M, int N, int K) {
  __shared__ __align__(16) bf16 As[128 * 32];
  __shared__ __align__(16) bf16 Bs[128 * 32];
  const int tid = threadIdx.x;
  const int lane = tid & 63;
  const int wid = tid >> 6;
  const int brow = blockIdx.y * 128;
  const int bcol = blockIdx.x * 128;
  const int wr = wid >> 1, wc = wid & 1;

  f32x4 acc[4][4] = {};

  const int srow = lane >> 2;
  const int scol = (lane & 3) * 8;
  const bf16* Ag = A + (long)(brow + wid * 32 + srow) * K + scol;
  const bf16* Bg = B + (long)(bcol + wid * 32 + srow) * K + scol;
  bf16* AsW = As + wid * 32 * 32;
  bf16* BsW = Bs + wid * 32 * 32;
  const int kof = (lane >> 4) * 8;
  const int r16 = lane & 15;

  for (int k0 = 0; k0 < K; k0 += 32) {
    __syncthreads();
    gload_lds16(Ag + k0, AsW);
    gload_lds16(Ag + k0 + (long)16 * K, AsW + 16 * 32);
    gload_lds16(Bg + k0, BsW);
    gload_lds16(Bg + k0 + (long)16 * K, BsW + 16 * 32);
    __syncthreads();
    bf16x8 af[4], bfr[4];
#pragma unroll
    for (int m = 0; m < 4; ++m)
      af[m] = *(const bf16x8*)(As + (wr * 64 + m * 16 + r16) * 32 + kof);
#pragma unroll
    for (int n = 0; n < 4; ++n)
      bfr[n] = *(const bf16x8*)(Bs + (wc * 64 + n * 16 + r16) * 32 + kof);
#pragma unroll
    for (int m = 0; m < 4; ++m)
#pragma unroll
      for (int n = 0; n < 4; ++n)
        acc[m][n] = mfma16(af[m], bfr[n], acc[m][n]);
  }

  const int r0 = (lane >> 4) * 4;
#pragma unroll
  for (int m = 0; m < 4; ++m) {
#pragma unroll
    for (int n = 0; n < 4; ++n) {
      int row = brow + wr * 64 + m * 16 + r0;
      int col = bcol + wc * 64 + n * 16 + r16;
#pragma unroll
      for (int r = 0; r < 4; ++r) {
        if (OUT_BF16) {
          ((bf16*)Cout)[(long)(row + r) * N + col] = __float2bfloat16(acc[m][n][r]);
        } else {
          ((float*)Cout)[(long)(row + r) * N + col] = acc[m][n][r] + bias[col];
        }
      }
    }
  }
}

// ---------------- causal flash attention (v5: paired-tile, shared KV) -------
// grid (256): block = head (bid&15) + TWO q-tiles: heavy qblk=31-tier (waves
// 0-3) and light qblk=tier (waves 4-7), tier = bid>>4. 512 thr = 8 waves;
// wave owns 32 q rows. Both tiles SHARE one KVBLK=128 double-buffered staging
// pipeline (64 KB LDS) -> per-block loop count 32-tier; per-CU work constant
// by construction; KV fetched once for two tiles.
// S^T = mfma32(K,Q^T): lane owns q=lane&31; softmax per-lane scalar; lane-pair
// (l, l^32) exchange via __shfl_xor(.,32). O^T = mfma32(V^T,P^T).
__global__ __launch_bounds__(512, 2) void attn_kernel(const bf16* __restrict__ qkv,
                                                      bf16* __restrict__ ctx) {
  __shared__ __align__(16) bf16 smem[32768];   // 64 KB
  bf16 (*Ks)[128][64] = (bf16(*)[128][64])(smem);           // 2 bufs, [kv][d]
  bf16 (*Vt)[64][128] = (bf16(*)[64][128])(smem + 16384);   // 2 bufs, [d][kv]

  const int tid = threadIdx.x;
  const int lane = tid & 63;
  const int wid = tid >> 6;            // 0..7
  const int hi = lane >> 5;
  const int l31 = lane & 31;
  const int tier = blockIdx.x >> 4;    // 0..15
  const int h = blockIdx.x & 15;
  const int wslot = wid & 3;
  const int qblk = (wid < 4) ? (31 - tier) : tier;
  const int q0w = qblk * 128 + wslot * 32;     // wave's q base
  const long kcol = DMODEL + (long)h * HD;
  const long vcol = 2 * DMODEL + (long)h * HD;
  const u16* qkv16 = (const u16*)qkv;

  // Q B-fragments: lane holds Q[q=l31][d = kt*16 + hi*8 .. +8]
  bf16x8 qf[4];
  {
    const bf16* qp = qkv + (long)(q0w + l31) * QKV_LD + h * HD + hi * 8;
#pragma unroll
    for (int kt = 0; kt < 4; ++kt) qf[kt] = *(const bf16x8*)(qp + kt * 16);
  }

  const int kOff = ((lane & 7) ^ (lane >> 3)) * 8;  // pre-swizzled K src col
  const int krow0 = wid * 16 + (lane >> 3);         // K stage row (this lane)

  f32x16 acc[2] = {};
  float m_r = -1e30f, l_r = 0.0f;

  const int nkb = 32 - tier;           // heavy tile's block count
  u16x8 va, vb;

  // prologue: stage KV block 0 into buf 0 (all 8 waves cooperate)
  {
#pragma unroll
    for (int c = 0; c < 2; ++c)
      gload_lds16(qkv + (long)(krow0 + c * 8) * QKV_LD + kcol + kOff,
                  &Ks[0][wid * 16 + c * 8][0]);
    const u16* vp = qkv16 + (long)(wid * 16) * QKV_LD + vcol + lane;
#pragma unroll
    for (int j = 0; j < 8; ++j) va[j] = vp[(long)j * QKV_LD];
#pragma unroll
    for (int j = 0; j < 8; ++j) vb[j] = vp[(long)(8 + j) * QKV_LD];
    *(u16x8*)(&Vt[0][lane][((wid * 2) ^ (lane & 15)) * 8]) = va;
    *(u16x8*)(&Vt[0][lane][((wid * 2 + 1) ^ (lane & 15)) * 8]) = vb;
  }

  for (int kb = 0; kb < nkb; ++kb) {
    const int cur = kb & 1;
    const int kv0 = kb * 128;
    const bool pre = (kb + 1 < nkb);
    __syncthreads();   // staging of block kb visible; prev iter reads done

    // prefetch next KV block: K -> LDS (other buf) async, V -> regs
    if (pre) {
      const long kvn = kv0 + 128;
#pragma unroll
      for (int c = 0; c < 2; ++c)
        gload_lds16(qkv + (kvn + krow0 + c * 8) * QKV_LD + kcol + kOff,
                    &Ks[cur ^ 1][wid * 16 + c * 8][0]);
      const u16* vp = qkv16 + (kvn + wid * 16) * QKV_LD + vcol + lane;
#pragma unroll
      for (int j = 0; j < 8; ++j) va[j] = vp[(long)j * QKV_LD];
#pragma unroll
      for (int j = 0; j < 8; ++j) vb[j] = vp[(long)(8 + j) * QKV_LD];
    }

#pragma unroll
    for (int sub = 0; sub < 4; ++sub) {
      const int kvs = kv0 + sub * 32;
      if (kvs > q0w + 31) continue;        // wave-uniform skip (incl. idle tile)
      const int krow = sub * 32 + l31;

      // S^T = K * Q^T over d=64 (4 mfma of k=16)
      f32x16 c16 = {};
#pragma unroll
      for (int kt = 0; kt < 4; ++kt) {
        bf16x8 kf = *(const bf16x8*)(&Ks[cur][krow][(((kt << 1) | hi) ^ (krow & 7)) * 8]);
        c16 = mfma32(kf, qf[kt], c16);
      }

      // causal mask (diagonal region only)
      if (kvs + 31 > q0w) {
        const int q = q0w + l31;
        const int kvb = kvs + 4 * hi;
#pragma unroll
        for (int r = 0; r < 16; ++r) {
          int kv = kvb + (r & 3) + 8 * (r >> 2);
          if (kv > q) c16[r] = -1e30f;
        }
      }

      // per-lane online softmax (q = l31); pair (l, l^32) holds the 32 kv
      float t0 = fmaxf(fmaxf(c16[0], c16[1]), fmaxf(c16[2], c16[3]));
      float t1 = fmaxf(fmaxf(c16[4], c16[5]), fmaxf(c16[6], c16[7]));
      float t2 = fmaxf(fmaxf(c16[8], c16[9]), fmaxf(c16[10], c16[11]));
      float t3 = fmaxf(fmaxf(c16[12], c16[13]), fmaxf(c16[14], c16[15]));
      float pmax = fmaxf(fmaxf(t0, t1), fmaxf(t2, t3));
      pmax = fmaxf(pmax, __shfl_xor(pmax, 32, 64));

      if (!__all(pmax <= m_r + 8.0f)) {    // defer-max (T13)
        float mn = fmaxf(m_r, pmax);
        float al = __expf(m_r - mn);
        m_r = mn;
        l_r *= al;
#pragma unroll
        for (int dt = 0; dt < 2; ++dt)
#pragma unroll
          for (int r = 0; r < 16; ++r) acc[dt][r] *= al;
      }

      float p[16];
#pragma unroll
      for (int r = 0; r < 16; ++r) p[r] = __expf(c16[r] - m_r);
      float rs = ((p[0] + p[1]) + (p[2] + p[3])) + ((p[4] + p[5]) + (p[6] + p[7])) +
                 (((p[8] + p[9]) + (p[10] + p[11])) + ((p[12] + p[13]) + (p[14] + p[15])));
      rs += __shfl_xor(rs, 32, 64);
      l_r += rs;

      // P^T -> B-fragments: pack pairs to bf16x2 words, exchange across l^32
      union BP { u32 u[4]; bf16x8 v; } f0, f1;
      {
        u32 x01 = pkbf(p[0], p[1]), x23 = pkbf(p[2], p[3]);
        u32 x45 = pkbf(p[4], p[5]), x67 = pkbf(p[6], p[7]);
        u32 s01 = __shfl_xor(x01, 32, 64), s23 = __shfl_xor(x23, 32, 64);
        u32 s45 = __shfl_xor(x45, 32, 64), s67 = __shfl_xor(x67, 32, 64);
        f0.u[0] = hi ? s45 : x01;
        f0.u[1] = hi ? s67 : x23;
        f0.u[2] = hi ? x45 : s01;
        f0.u[3] = hi ? x67 : s23;
      }
      {
        u32 x01 = pkbf(p[8], p[9]), x23 = pkbf(p[10], p[11]);
        u32 x45 = pkbf(p[12], p[13]), x67 = pkbf(p[14], p[15]);
        u32 s01 = __shfl_xor(x01, 32, 64), s23 = __shfl_xor(x23, 32, 64);
        u32 s45 = __shfl_xor(x45, 32, 64), s67 = __shfl_xor(x67, 32, 64);
        f1.u[0] = hi ? s45 : x01;
        f1.u[1] = hi ? s67 : x23;
        f1.u[2] = hi ? x45 : s01;
        f1.u[3] = hi ? x67 : s23;
      }

      // O^T += V^T * P^T
#pragma unroll
      for (int dt = 0; dt < 2; ++dt) {
        const int vrow = dt * 32 + l31;
        bf16x8 vf0 = *(const bf16x8*)(&Vt[cur][vrow][((sub * 4 + hi) ^ (vrow & 15)) * 8]);
        acc[dt] = mfma32(vf0, f0.v, acc[dt]);
        bf16x8 vf1 = *(const bf16x8*)(&Vt[cur][vrow][((sub * 4 + 2 + hi) ^ (vrow & 15)) * 8]);
        acc[dt] = mfma32(vf1, f1.v, acc[dt]);
      }
    }

    // write staged V regs into the other buffer
    if (pre) {
      const int nb = cur ^ 1;
      *(u16x8*)(&Vt[nb][lane][((wid * 2) ^ (lane & 15)) * 8]) = va;
      *(u16x8*)(&Vt[nb][lane][((wid * 2 + 1) ^ (lane & 15)) * 8]) = vb;
    }
  }

  __syncthreads();   // all waves done with Ks/Vt; LDS reused for epilogue

  // epilogue: O^T regs -> per-wave LDS [32 q][68 d] -> coalesced ctx store
  bf16* scr = smem + wid * 2176;
  const float inv = 1.0f / l_r;
#pragma unroll
  for (int dt = 0; dt < 2; ++dt)
#pragma unroll
    for (int g2 = 0; g2 < 4; ++g2) {
      union { u16 hh[4]; unsigned long long q8; } pk4;
#pragma unroll
      for (int j = 0; j < 4; ++j) pk4.hh[j] = f2b(acc[dt][g2 * 4 + j] * inv);
      *(unsigned long long*)(scr + l31 * 68 + dt * 32 + g2 * 8 + 4 * hi) = pk4.q8;
    }
  __syncthreads();   // writes ordered & visible before cross-lane reads

  const int qe = lane >> 1, he = lane & 1;
  u16* cp = (u16*)ctx + (long)(q0w + qe) * DMODEL + h * HD + he * 32;
#pragma unroll
  for (int j = 0; j < 4; ++j) {
    u16x8 v = *(const u16x8*)(scr + qe * 68 + he * 32 + j * 8);
    *(u16x8*)(cp + j * 8) = v;
  }
}

extern "C" void kernel_launch(void* const* d_in, const int* in_sizes, int n_in,
                              void* d_out, int out_size, void* d_ws, size_t ws_size,
                              hipStream_t stream) {
  (void)in_sizes; (void)n_in; (void)out_size; (void)ws_size;
  const float* x  = (const float*)d_in[0];
  const float* Wq = (const float*)d_in[1];
  const float* Wk = (const float*)d_in[2];
  const float* Wv = (const float*)d_in[3];
  const float* Wo = (const float*)d_in[4];
  const float* bo = (const float*)d_in[5];
  float* out = (float*)d_out;

  char* ws = (char*)d_ws;
  bf16* xb   = (bf16*)(ws);                   //  8 MB: x in bf16 [4096,1024]
  bf16* wqkv = (bf16*)(ws + 8388608);         //  6 MB: packed Wq;Wk;Wv [3072,1024]
  bf16* wob  = (bf16*)(ws + 14680064);        //  2 MB: Wo [1024,1024]
  bf16* qkvb = (bf16*)(ws + 16777216);        // 24 MB: QKV [4096,3072]
  bf16* ctxb = (bf16*)(ws + 41943040);        //  8 MB: ctx [4096,1024]

  cvt_kernel<<<dim3(4096), dim3(256), 0, stream>>>(x, xb, 4194304);
  cvt_kernel<<<dim3(1024), dim3(256), 0, stream>>>(Wq, wqkv, 1048576);
  cvt_kernel<<<dim3(1024), dim3(256), 0, stream>>>(Wk, wqkv + 1048576, 1048576);
  cvt_kernel<<<dim3(1024), dim3(256), 0, stream>>>(Wv, wqkv + 2097152, 1048576);
  cvt_kernel<<<dim3(1024), dim3(256), 0, stream>>>(Wo, wob, 1048576);

  gemm_bt<1><<<dim3(24, 32), dim3(256), 0, stream>>>(xb, wqkv, (void*)qkvb, nullptr,
                                                     4096, 3072, 1024);
  rope_kernel<<<dim3(16384), dim3(256), 0, stream>>>(qkvb);
  attn_kernel<<<dim3(256), dim3(512), 0, stream>>>(qkvb, ctxb);
  gemm_bt<0><<<dim3(8, 32), dim3(256), 0, stream>>>(ctxb, wob, (void*)out, bo,
                                                    4096, 1024, 1024);
}